// Round 1
// baseline (44.796 us; speedup 1.0000x reference)
//
#include <hip/hip_runtime.h>
#include <cstdint>

#define BIGKEY 0x7FFFFFFF
#define TPB 128   // one thread per row

__global__ __launch_bounds__(TPB)
void pl_main(const float* __restrict__ scores,
             const int* __restrict__ ranks,
             const int* __restrict__ mask,
             float* __restrict__ partials,
             int B)
{
    const int tid = threadIdx.x;
    const int row = blockIdx.x * TPB + tid;

    float per_row = 0.0f, cnt = 0.0f;

    if (row < B) {
        const float4* sp = reinterpret_cast<const float4*>(scores) + (size_t)row * 8;
        const int4*   rp = reinterpret_cast<const int4*>(ranks)  + (size_t)row * 8;
        const int4*   mp = reinterpret_cast<const int4*>(mask)   + (size_t)row * 8;

        float s[32];
        int   K[32];

        #pragma unroll
        for (int c = 0; c < 8; ++c) {
            float4 sv = sp[c];
            int4   rv = rp[c];
            int4   mv = mp[c];
            const int j = c * 4;
            s[j+0] = sv.x; s[j+1] = sv.y; s[j+2] = sv.z; s[j+3] = sv.w;
            // key = rank*32 + index encodes the stable sort order; masked -> BIGKEY
            K[j+0] = (mv.x == 0) ? (rv.x * 32 + j + 0) : BIGKEY;
            K[j+1] = (mv.y == 0) ? (rv.y * 32 + j + 1) : BIGKEY;
            K[j+2] = (mv.z == 0) ? (rv.z * 32 + j + 2) : BIGKEY;
            K[j+3] = (mv.w == 0) ? (rv.w * 32 + j + 3) : BIGKEY;
        }

        // n valid, row max over valid, sum of valid scores
        int n = 0;
        float mx = -3.0e38f;
        float Ssum = 0.0f;
        #pragma unroll
        for (int j = 0; j < 32; ++j) {
            const bool v = (K[j] != BIGKEY);
            n    += v ? 1 : 0;
            mx    = fmaxf(mx, v ? s[j] : -3.0e38f);
            Ssum += v ? s[j] : 0.0f;
        }

        // e_j = exp(s_j - mx) (base-2 internally), masked -> exactly 0
        #pragma unroll
        for (int j = 0; j < 32; ++j) {
            const bool v = (K[j] != BIGKEY);
            s[j] = v ? exp2f((s[j] - mx) * 1.4426950408889634f) : 0.0f;
        }

        // all-pairs suffix sums in sorted order: T_i = sum_j e_j * [key_j >= key_i]
        float lsum = 0.0f;  // sum over valid i of log2(T_i)
        #pragma unroll
        for (int i = 0; i < 32; ++i) {
            float t0 = 0.0f, t1 = 0.0f, t2 = 0.0f, t3 = 0.0f;
            const int ki = K[i];
            #pragma unroll
            for (int j = 0; j < 32; j += 4) {
                t0 += (K[j+0] >= ki) ? s[j+0] : 0.0f;
                t1 += (K[j+1] >= ki) ? s[j+1] : 0.0f;
                t2 += (K[j+2] >= ki) ? s[j+2] : 0.0f;
                t3 += (K[j+3] >= ki) ? s[j+3] : 0.0f;
            }
            const float Ti = (t0 + t1) + (t2 + t3);
            lsum += (ki != BIGKEY) ? __log2f(fmaxf(Ti, 1e-37f)) : 0.0f;
        }

        if (n >= 2) {
            // loss = sum_valid (m + ln(T_i) - s_i) = ln2*lsum - (Ssum - n*m)
            const float loss = 0.69314718055994531f * lsum - (Ssum - (float)n * mx);
            per_row = loss / (float)n;
            cnt = 1.0f;
        }
    }

    // wave reduce (width 64), then combine the block's 2 waves via tiny LDS
    #pragma unroll
    for (int d = 32; d >= 1; d >>= 1) {
        per_row += __shfl_xor(per_row, d, 64);
        cnt     += __shfl_xor(cnt,     d, 64);
    }
    __shared__ float rbuf[4];
    if ((tid & 63) == 0) {
        rbuf[(tid >> 6)]     = per_row;
        rbuf[2 + (tid >> 6)] = cnt;
    }
    __syncthreads();
    if (tid == 0) {
        partials[2 * blockIdx.x]     = rbuf[0] + rbuf[1];
        partials[2 * blockIdx.x + 1] = rbuf[2] + rbuf[3];
    }
}

__global__ __launch_bounds__(256)
void pl_final(const float* __restrict__ partials, int nb, float* __restrict__ out)
{
    const int tid = threadIdx.x;
    float s = 0.0f, c = 0.0f;
    for (int i = tid; i < nb; i += 256) {
        s += partials[2 * i];
        c += partials[2 * i + 1];
    }
    #pragma unroll
    for (int d = 32; d >= 1; d >>= 1) {
        s += __shfl_xor(s, d, 64);
        c += __shfl_xor(c, d, 64);
    }
    __shared__ float sb[8];
    if ((tid & 63) == 0) {
        sb[tid >> 6]     = s;
        sb[4 + (tid >> 6)] = c;
    }
    __syncthreads();
    if (tid == 0) {
        const float S = sb[0] + sb[1] + sb[2] + sb[3];
        const float C = sb[4] + sb[5] + sb[6] + sb[7];
        out[0] = S / fmaxf(C, 1.0f);
    }
}

extern "C" void kernel_launch(void* const* d_in, const int* in_sizes, int n_in,
                              void* d_out, int out_size, void* d_ws, size_t ws_size,
                              hipStream_t stream)
{
    const float* scores = (const float*)d_in[0];
    const int*   ranks  = (const int*)d_in[1];
    const int*   mask   = (const int*)d_in[2];

    const int B  = in_sizes[0] / 32;
    const int nb = (B + TPB - 1) / TPB;

    float* partials = (float*)d_ws;  // nb * 2 floats (16 KB at B=262144)

    pl_main<<<nb, TPB, 0, stream>>>(scores, ranks, mask, partials, B);
    pl_final<<<1, 256, 0, stream>>>(partials, nb, (float*)d_out);
}

// Round 2
// 26.426 us; speedup vs baseline: 1.6951x; 1.6951x over previous
//
#include <hip/hip_runtime.h>
#include <cstdint>

#define TPB 128   // one thread per row
#define LOG2E 1.4426950408889634f
#define LN2   0.69314718055994531f

__global__ __launch_bounds__(TPB)
void pl_main(const float* __restrict__ scores,
             const int* __restrict__ ranks,
             const int* __restrict__ mask,
             float* __restrict__ partials,
             int B)
{
    const int tid = threadIdx.x;
    const int row = blockIdx.x * TPB + tid;

    // e-table: slot j of thread t at eb[j*TPB + t] -> bank t%32, conflict-free
    // for both the compile-time-offset writes and the data-dependent gathers.
    // Each thread only touches its own column -> no __syncthreads needed.
    __shared__ float eb[32 * TPB];

    float per_row = 0.0f, cnt = 0.0f;

    if (row < B) {
        const float4* sp = reinterpret_cast<const float4*>(scores) + (size_t)row * 8;
        const int4*   rp = reinterpret_cast<const int4*>(ranks)  + (size_t)row * 8;
        const int4*   mp = reinterpret_cast<const int4*>(mask)   + (size_t)row * 8;

        float    s[32];
        unsigned K[32];

        // ---- load + build keys: key = mask*1024 + rank*32 + j  (unique, 11-bit)
        // valid keys < 1024 sort before all masked keys; key & 31 == j always.
        #pragma unroll
        for (int c = 0; c < 8; ++c) {
            float4 sv = sp[c];
            int4   rv = rp[c];
            int4   qv = mp[c];
            const int j = c * 4;
            s[j+0] = sv.x; s[j+1] = sv.y; s[j+2] = sv.z; s[j+3] = sv.w;
            K[j+0] = (unsigned)((qv.x << 10) + (rv.x << 5) + (j + 0));
            K[j+1] = (unsigned)((qv.y << 10) + (rv.y << 5) + (j + 1));
            K[j+2] = (unsigned)((qv.z << 10) + (rv.z << 5) + (j + 2));
            K[j+3] = (unsigned)((qv.w << 10) + (rv.w << 5) + (j + 3));
        }

        // ---- n (valid count) and row max (over ALL entries — any shift m works,
        // since loss = n*m + ln2*sum(log2 T') - Ssum holds for arbitrary m)
        int n = 0;
        float mx = -3.0e38f;
        #pragma unroll
        for (int j = 0; j < 32; ++j) {
            n += (K[j] < 1024u) ? 1 : 0;
            mx = fmaxf(mx, s[j]);
        }
        const float xm = mx * LOG2E;

        // ---- e_j = exp(s_j - m), masked -> 0; Ssum over valid; write e to LDS
        float Ssum = 0.0f;
        #pragma unroll
        for (int j = 0; j < 32; ++j) {
            const bool valid = (K[j] < 1024u);
            float x = __builtin_fmaf(s[j], LOG2E, -xm);
            float e = __builtin_amdgcn_exp2f(x);
            e = valid ? e : 0.0f;
            Ssum += valid ? s[j] : 0.0f;
            eb[j * TPB + tid] = e;
        }

        // ---- key-only bitonic sort, ascending; all indices/directions
        // compile-time after unroll -> 2 VALU (v_min_u32/v_max_u32) per comparator
        #pragma unroll
        for (int kk = 2; kk <= 32; kk <<= 1) {
            #pragma unroll
            for (int jj = kk >> 1; jj > 0; jj >>= 1) {
                #pragma unroll
                for (int i = 0; i < 32; ++i) {
                    const int l = i ^ jj;
                    if (l > i) {
                        const unsigned a = K[i], b = K[l];
                        const unsigned mn = a < b ? a : b;
                        const unsigned mh = a < b ? b : a;
                        if ((i & kk) == 0) { K[i] = mn; K[l] = mh; }
                        else               { K[i] = mh; K[l] = mn; }
                    }
                }
            }
        }

        // ---- gather e in sorted order (padded slots fetch the stored 0)
        float es[32];
        #pragma unroll
        for (int p = 0; p < 32; ++p) {
            es[p] = eb[(K[p] & 31u) * TPB + tid];
        }

        // ---- reverse suffix sums T_p; sum log2(T_p) over valid p via
        // product-of-4 groups (range-safe: each factor in [e^-12, 32])
        float t = 0.0f, lsum = 0.0f;
        #pragma unroll
        for (int g = 7; g >= 0; --g) {
            float prod = 1.0f;
            #pragma unroll
            for (int q = 3; q >= 0; --q) {
                const int p = 4 * g + q;
                t += es[p];
                prod *= (K[p] < 1024u) ? t : 1.0f;
            }
            lsum += __builtin_amdgcn_logf(prod);   // hw log2
        }

        if (n >= 2) {
            const float loss = (float)n * mx + LN2 * lsum - Ssum;
            per_row = loss / (float)n;
            cnt = 1.0f;
        }
    }

    // ---- wave reduce (width 64), then combine the block's 2 waves
    #pragma unroll
    for (int d = 32; d >= 1; d >>= 1) {
        per_row += __shfl_xor(per_row, d, 64);
        cnt     += __shfl_xor(cnt,     d, 64);
    }
    __shared__ float rbuf[4];
    if ((tid & 63) == 0) {
        rbuf[(tid >> 6)]     = per_row;
        rbuf[2 + (tid >> 6)] = cnt;
    }
    __syncthreads();
    if (tid == 0) {
        partials[2 * blockIdx.x]     = rbuf[0] + rbuf[1];
        partials[2 * blockIdx.x + 1] = rbuf[2] + rbuf[3];
    }
}

__global__ __launch_bounds__(256)
void pl_final(const float* __restrict__ partials, int nb, float* __restrict__ out)
{
    const int tid = threadIdx.x;
    float s = 0.0f, c = 0.0f;
    for (int i = tid; i < nb; i += 256) {
        s += partials[2 * i];
        c += partials[2 * i + 1];
    }
    #pragma unroll
    for (int d = 32; d >= 1; d >>= 1) {
        s += __shfl_xor(s, d, 64);
        c += __shfl_xor(c, d, 64);
    }
    __shared__ float sb[8];
    if ((tid & 63) == 0) {
        sb[tid >> 6]       = s;
        sb[4 + (tid >> 6)] = c;
    }
    __syncthreads();
    if (tid == 0) {
        const float S = sb[0] + sb[1] + sb[2] + sb[3];
        const float C = sb[4] + sb[5] + sb[6] + sb[7];
        out[0] = S / fmaxf(C, 1.0f);
    }
}

extern "C" void kernel_launch(void* const* d_in, const int* in_sizes, int n_in,
                              void* d_out, int out_size, void* d_ws, size_t ws_size,
                              hipStream_t stream)
{
    const float* scores = (const float*)d_in[0];
    const int*   ranks  = (const int*)d_in[1];
    const int*   mask   = (const int*)d_in[2];

    const int B  = in_sizes[0] / 32;
    const int nb = (B + TPB - 1) / TPB;

    float* partials = (float*)d_ws;  // nb * 2 floats

    pl_main<<<nb, TPB, 0, stream>>>(scores, ranks, mask, partials, B);
    pl_final<<<1, 256, 0, stream>>>(partials, nb, (float*)d_out);
}